// Round 12
// baseline (375.136 us; speedup 1.0000x reference)
//
#include <hip/hip_runtime.h>

typedef __attribute__((ext_vector_type(4))) float f32x4;
typedef __attribute__((ext_vector_type(8))) short s16x8;
typedef __attribute__((ext_vector_type(4))) unsigned short u16x4;

#define NH 16
#define SEQ 2048
#define WIDTH 3072
#define DH 64
#define KVB 64
#define NT (SEQ / KVB)
#define QSCALE 0.125f  /* scale^2 folded into Q */
#define SHIFT 8.0f     /* folded into MFMA C-init; p = e^(s-8), exact after final divide */

__device__ __forceinline__ unsigned short f2bf(float f) {
  union { __bf16 b; unsigned short u; } cv;
  cv.b = (__bf16)f;  // compiler fuses adjacent pairs into v_cvt_pk_bf16_f32
  return cv.u;
}

// 4 waves x 16 q-rows = 64 q-rows/block; grid 1024 = 4 blocks/CU, 16 waves/CU.
__global__ __launch_bounds__(256, 4) void attn_fwd(const float* __restrict__ qkv,
                                                   float* __restrict__ out) {
  // XCD-bijective swizzle: 1024 blocks, 128 consecutive per XCD (4 heads' K/V = 4MB L2)
  int bid0 = (int)blockIdx.x;
  int bid = (bid0 & 7) * 128 + (bid0 >> 3);
  const int qb = bid & 31;          // q-block of 64 rows
  const int h  = (bid >> 5) & 15;   // head
  const int b  = bid >> 9;          // batch

  const int tid  = (int)threadIdx.x;
  const int lane = tid & 63;
  const int wid  = tid >> 6;
  const int col  = lane & 15;
  const int hi   = lane >> 4;
  const int cx   = (col & 7) << 3;   // read-side XOR swizzle (elem units)

  // [row][64] bf16, elem ^= (row&7)<<3 — matched-involution swizzle (0 conflicts, r9-verified)
  __shared__ __align__(16) unsigned short sK[2][KVB * 64];
  __shared__ __align__(16) unsigned short sV[2][DH * 64];  // Vt[d][key-position], PA-slot order

  const size_t base = (size_t)b * SEQ * WIDTH + (size_t)h * (3 * DH);
  const int q0 = qb * 64 + wid * 16;

  // ---- Q B-frags (QSCALE folded): n=q=col, k=32c+8hi+j ----
  s16x8 qf[2];
  {
    const float* qp = qkv + base + (size_t)(q0 + col) * WIDTH;
#pragma unroll
    for (int c = 0; c < 2; ++c) {
      const f32x4 f0 = *(const f32x4*)(qp + 32 * c + 8 * hi);
      const f32x4 f1 = *(const f32x4*)(qp + 32 * c + 8 * hi + 4);
      s16x8 v;
#pragma unroll
      for (int j = 0; j < 4; ++j) {
        v[j]     = (short)f2bf(f0[j] * QSCALE);
        v[4 + j] = (short)f2bf(f1[j] * QSCALE);
      }
      qf[c] = v;
    }
  }

  f32x4 oacc[4];
  float l_ = 0.0f;
#pragma unroll
  for (int nc = 0; nc < 4; ++nc)
#pragma unroll
    for (int r = 0; r < 4; ++r) oacc[nc][r] = 0.0f;

  // staging decomposition — identical to round 9 (measured 0 bank conflicts)
  const int krow = tid >> 2, kdc = (tid & 3) * 16;  // K: 1 row x 16 floats (64B contiguous)
  const int vrg = tid & 15, vdg = tid >> 4;         // V: 4 keys x 4 d, register transpose
  // permuted key position: key 4vrg+t -> pos pbase+t (PA slot order)
  const int pbase = 32 * (vrg >> 3) + 8 * (vrg & 3) + 4 * ((vrg >> 2) & 1);

  f32x4 kr[4], vr[4];

  auto load_tile = [&](int t) {
    const float* kg = qkv + base + (size_t)(t * KVB + krow) * WIDTH + DH + kdc;
#pragma unroll
    for (int i = 0; i < 4; ++i) kr[i] = *(const f32x4*)(kg + 4 * i);
    const float* vg = qkv + base + (size_t)(t * KVB + vrg * 4) * WIDTH + 2 * DH + vdg * 4;
#pragma unroll
    for (int rr = 0; rr < 4; ++rr) vr[rr] = *(const f32x4*)(vg + (size_t)rr * WIDTH);
  };

  auto write_tile = [&](int pb) {
#pragma unroll
    for (int i = 0; i < 2; ++i) {  // K: 2 x b128 at the bank floor
      s16x8 w;
#pragma unroll
      for (int j = 0; j < 4; ++j) {
        w[j]     = (short)f2bf(kr[2 * i][j]);
        w[4 + j] = (short)f2bf(kr[2 * i + 1][j]);
      }
      const int e = (krow * 64 + kdc + 8 * i) ^ ((krow & 7) << 3);
      *(s16x8*)&sK[pb][e] = w;
    }
#pragma unroll
    for (int dd = 0; dd < 4; ++dd) {  // Vt: 4 x b64 at permuted positions
      const int d = vdg * 4 + dd;
      u16x4 w;
#pragma unroll
      for (int rr = 0; rr < 4; ++rr) w[rr] = f2bf(vr[rr][dd]);
      const int e = (d * 64 + pbase) ^ ((d & 7) << 3);
      *(u16x4*)&sV[pb][e] = w;
    }
  };

  load_tile(0);
  write_tile(0);

  for (int t = 0; t < NT; ++t) {
    const int pb = t & 1;
    __syncthreads();                     // one barrier/tile (dbuf-safe)
    if (t + 1 < NT) load_tile(t + 1);    // global->regs in flight under compute

    // K A-frags: m=key=16g+col, k=32c+8hi+j
    s16x8 kf[4][2];
#pragma unroll
    for (int g = 0; g < 4; ++g)
#pragma unroll
      for (int c = 0; c < 2; ++c)
        kf[g][c] = *(const s16x8*)&sK[pb][((16 * g + col) * 64 + 32 * c + 8 * hi) ^ cx];

    // V B-frags: one b128 each (keys pre-permuted to PA slot order at store time)
    s16x8 vf[2][4];
#pragma unroll
    for (int u = 0; u < 2; ++u)
#pragma unroll
      for (int nc = 0; nc < 4; ++nc)
        vf[u][nc] = *(const s16x8*)&sV[pb][((16 * nc + col) * 64 + 32 * u + 8 * hi) ^ cx];

    // swapped QK^T: S[key=16g+4hi+r][q=col], C pre-initialized to -SHIFT
    f32x4 sa[4];
#pragma unroll
    for (int g = 0; g < 4; ++g)
#pragma unroll
      for (int r = 0; r < 4; ++r) sa[g][r] = -SHIFT;
    __builtin_amdgcn_s_setprio(1);
#pragma unroll
    for (int g = 0; g < 4; ++g)
#pragma unroll
      for (int c = 0; c < 2; ++c)
        sa[g] = __builtin_amdgcn_mfma_f32_16x16x32_bf16(kf[g][c], qf[c], sa[g], 0, 0, 0);
    __builtin_amdgcn_s_setprio(0);

    // fixed-shift softmax: one __expf per score (shift already in C)
    float pr[16];
#pragma unroll
    for (int g = 0; g < 4; ++g)
#pragma unroll
      for (int r = 0; r < 4; ++r) pr[g * 4 + r] = __expf(sa[g][r]);
    // tree-summed l
    const float t0 = (pr[0] + pr[1]) + (pr[2] + pr[3]);
    const float t1 = (pr[4] + pr[5]) + (pr[6] + pr[7]);
    const float t2 = (pr[8] + pr[9]) + (pr[10] + pr[11]);
    const float t3 = (pr[12] + pr[13]) + (pr[14] + pr[15]);
    l_ += (t0 + t1) + (t2 + t3);

    // PA A-frags: slot j -> pr[8u+j] (matches vf key permutation)
    s16x8 pa[2];
#pragma unroll
    for (int u = 0; u < 2; ++u) {
      s16x8 w;
#pragma unroll
      for (int j = 0; j < 8; ++j) w[j] = (short)f2bf(pr[8 * u + j]);
      pa[u] = w;
    }
    __builtin_amdgcn_s_setprio(1);
#pragma unroll
    for (int u = 0; u < 2; ++u)
#pragma unroll
      for (int nc = 0; nc < 4; ++nc)
        oacc[nc] = __builtin_amdgcn_mfma_f32_16x16x32_bf16(pa[u], vf[u][nc], oacc[nc], 0, 0, 0);
    __builtin_amdgcn_s_setprio(0);

    if (t + 1 < NT) write_tile((t + 1) & 1);
  }

  // ---- epilogue: l reduce (once), normalize, store ----
  {
    float lv = l_;
    lv += __shfl_xor(lv, 16);
    lv += __shfl_xor(lv, 32);   // lv = l_total[q=col] on every lane
#pragma unroll
    for (int r = 0; r < 4; ++r) {
      const float lt = __shfl(lv, 4 * hi + r);   // l for this lane's output row
      const float inv = 1.0f / lt;
      const int q = q0 + 4 * hi + r;
      float* op = out + ((size_t)b * SEQ + q) * (NH * DH) + h * DH;
#pragma unroll
      for (int nc = 0; nc < 4; ++nc)
        op[nc * 16 + col] = oacc[nc][r] * inv;
    }
  }
}

extern "C" void kernel_launch(void* const* d_in, const int* in_sizes, int n_in,
                              void* d_out, int out_size, void* d_ws, size_t ws_size,
                              hipStream_t stream) {
  const float* qkv = (const float*)d_in[0];
  float* out = (float*)d_out;
  (void)in_sizes; (void)n_in; (void)out_size; (void)d_ws; (void)ws_size;
  attn_fwd<<<dim3(1024), dim3(256), 0, stream>>>(qkv, out);
}

// Round 13
// 177.703 us; speedup vs baseline: 2.1110x; 2.1110x over previous
//
#include <hip/hip_runtime.h>

typedef __attribute__((ext_vector_type(4))) float f32x4;
typedef __attribute__((ext_vector_type(8))) short s16x8;
typedef __attribute__((ext_vector_type(4))) unsigned short u16x4;

#define NH 16
#define SEQ 2048
#define WIDTH 3072
#define DH 64
#define KVB 64
#define NT (SEQ / KVB)
#define QSCALE 0.125f  /* scale^2 folded into Q */
#define SHIFT 8.0f     /* folded into MFMA C-init; p = e^(s-8), exact after final divide */

__device__ __forceinline__ unsigned short f2bf(float f) {
  union { __bf16 b; unsigned short u; } cv;
  cv.b = (__bf16)f;  // compiler fuses adjacent pairs into v_cvt_pk_bf16_f32
  return cv.u;
}

// 4 waves x 16 q-rows = 64 q-rows/block; grid 1024 -> 4 blocks/CU, 16 waves/CU.
// NOTE: bounds (256,2) NOT (256,4) — a tighter bound splits the unified reg file
// 64arch/64acc and spills ~0.7GB/launch (measured r11/r12). (256,2) -> ~95 arch regs,
// and the HW occupancy limit floor(512/VGPR) still admits 4 blocks/CU.
__global__ __launch_bounds__(256, 2) void attn_fwd(const float* __restrict__ qkv,
                                                   float* __restrict__ out) {
  // XCD-bijective swizzle: 1024 blocks, 128 consecutive per XCD (4 heads' K/V = 4MB L2)
  int bid0 = (int)blockIdx.x;
  int bid = (bid0 & 7) * 128 + (bid0 >> 3);
  const int qb = bid & 31;          // q-block of 64 rows
  const int h  = (bid >> 5) & 15;   // head
  const int b  = bid >> 9;          // batch

  const int tid  = (int)threadIdx.x;
  const int lane = tid & 63;
  const int wid  = tid >> 6;
  const int col  = lane & 15;
  const int hi   = lane >> 4;
  const int cx   = (col & 7) << 3;   // read-side XOR swizzle (elem units)

  // [row][64] bf16, elem ^= (row&7)<<3 — matched-involution swizzle (0 conflicts, r9-verified)
  __shared__ __align__(16) unsigned short sK[2][KVB * 64];
  __shared__ __align__(16) unsigned short sV[2][DH * 64];  // Vt[d][key-position], PA-slot order

  const size_t base = (size_t)b * SEQ * WIDTH + (size_t)h * (3 * DH);
  const int q0 = qb * 64 + wid * 16;

  // ---- Q B-frags (QSCALE folded): n=q=col, k=32c+8hi+j ----
  s16x8 qf[2];
  {
    const float* qp = qkv + base + (size_t)(q0 + col) * WIDTH;
#pragma unroll
    for (int c = 0; c < 2; ++c) {
      const f32x4 f0 = *(const f32x4*)(qp + 32 * c + 8 * hi);
      const f32x4 f1 = *(const f32x4*)(qp + 32 * c + 8 * hi + 4);
      s16x8 v;
#pragma unroll
      for (int j = 0; j < 4; ++j) {
        v[j]     = (short)f2bf(f0[j] * QSCALE);
        v[4 + j] = (short)f2bf(f1[j] * QSCALE);
      }
      qf[c] = v;
    }
  }

  f32x4 oacc[4];
  float l_ = 0.0f;
#pragma unroll
  for (int nc = 0; nc < 4; ++nc)
#pragma unroll
    for (int r = 0; r < 4; ++r) oacc[nc][r] = 0.0f;

  // staging decomposition — identical to round 9 (measured 0 bank conflicts)
  const int krow = tid >> 2, kdc = (tid & 3) * 16;  // K: 1 row x 16 floats (64B contiguous)
  const int vrg = tid & 15, vdg = tid >> 4;         // V: 4 keys x 4 d, register transpose
  // permuted key position: key 4vrg+t -> pos pbase+t (PA slot order)
  const int pbase = 32 * (vrg >> 3) + 8 * (vrg & 3) + 4 * ((vrg >> 2) & 1);

  f32x4 kr[4], vr[4];

  auto load_tile = [&](int t) {
    const float* kg = qkv + base + (size_t)(t * KVB + krow) * WIDTH + DH + kdc;
#pragma unroll
    for (int i = 0; i < 4; ++i) kr[i] = *(const f32x4*)(kg + 4 * i);
    const float* vg = qkv + base + (size_t)(t * KVB + vrg * 4) * WIDTH + 2 * DH + vdg * 4;
#pragma unroll
    for (int rr = 0; rr < 4; ++rr) vr[rr] = *(const f32x4*)(vg + (size_t)rr * WIDTH);
  };

  auto write_tile = [&](int pb) {
#pragma unroll
    for (int i = 0; i < 2; ++i) {  // K: 2 x b128 at the bank floor
      s16x8 w;
#pragma unroll
      for (int j = 0; j < 4; ++j) {
        w[j]     = (short)f2bf(kr[2 * i][j]);
        w[4 + j] = (short)f2bf(kr[2 * i + 1][j]);
      }
      const int e = (krow * 64 + kdc + 8 * i) ^ ((krow & 7) << 3);
      *(s16x8*)&sK[pb][e] = w;
    }
#pragma unroll
    for (int dd = 0; dd < 4; ++dd) {  // Vt: 4 x b64 at permuted positions
      const int d = vdg * 4 + dd;
      u16x4 w;
#pragma unroll
      for (int rr = 0; rr < 4; ++rr) w[rr] = f2bf(vr[rr][dd]);
      const int e = (d * 64 + pbase) ^ ((d & 7) << 3);
      *(u16x4*)&sV[pb][e] = w;
    }
  };

  load_tile(0);
  write_tile(0);

  for (int t = 0; t < NT; ++t) {
    const int pb = t & 1;
    __syncthreads();                     // one barrier/tile (dbuf-safe)
    if (t + 1 < NT) load_tile(t + 1);    // global->regs in flight under compute

    // K A-frags: m=key=16g+col, k=32c+8hi+j
    s16x8 kf[4][2];
#pragma unroll
    for (int g = 0; g < 4; ++g)
#pragma unroll
      for (int c = 0; c < 2; ++c)
        kf[g][c] = *(const s16x8*)&sK[pb][((16 * g + col) * 64 + 32 * c + 8 * hi) ^ cx];

    // V B-frags: one b128 each (keys pre-permuted to PA slot order at store time)
    s16x8 vf[2][4];
#pragma unroll
    for (int u = 0; u < 2; ++u)
#pragma unroll
      for (int nc = 0; nc < 4; ++nc)
        vf[u][nc] = *(const s16x8*)&sV[pb][((16 * nc + col) * 64 + 32 * u + 8 * hi) ^ cx];

    // swapped QK^T: S[key=16g+4hi+r][q=col], C pre-initialized to -SHIFT
    f32x4 sa[4];
#pragma unroll
    for (int g = 0; g < 4; ++g)
#pragma unroll
      for (int r = 0; r < 4; ++r) sa[g][r] = -SHIFT;
    __builtin_amdgcn_s_setprio(1);
#pragma unroll
    for (int g = 0; g < 4; ++g)
#pragma unroll
      for (int c = 0; c < 2; ++c)
        sa[g] = __builtin_amdgcn_mfma_f32_16x16x32_bf16(kf[g][c], qf[c], sa[g], 0, 0, 0);
    __builtin_amdgcn_s_setprio(0);

    // fixed-shift softmax: one __expf per score (shift already in C)
    float pr[16];
#pragma unroll
    for (int g = 0; g < 4; ++g)
#pragma unroll
      for (int r = 0; r < 4; ++r) pr[g * 4 + r] = __expf(sa[g][r]);
    // tree-summed l
    const float t0 = (pr[0] + pr[1]) + (pr[2] + pr[3]);
    const float t1 = (pr[4] + pr[5]) + (pr[6] + pr[7]);
    const float t2 = (pr[8] + pr[9]) + (pr[10] + pr[11]);
    const float t3 = (pr[12] + pr[13]) + (pr[14] + pr[15]);
    l_ += (t0 + t1) + (t2 + t3);

    // PA A-frags: slot j -> pr[8u+j] (matches vf key permutation)
    s16x8 pa[2];
#pragma unroll
    for (int u = 0; u < 2; ++u) {
      s16x8 w;
#pragma unroll
      for (int j = 0; j < 8; ++j) w[j] = (short)f2bf(pr[8 * u + j]);
      pa[u] = w;
    }
    __builtin_amdgcn_s_setprio(1);
#pragma unroll
    for (int u = 0; u < 2; ++u)
#pragma unroll
      for (int nc = 0; nc < 4; ++nc)
        oacc[nc] = __builtin_amdgcn_mfma_f32_16x16x32_bf16(pa[u], vf[u][nc], oacc[nc], 0, 0, 0);
    __builtin_amdgcn_s_setprio(0);

    if (t + 1 < NT) write_tile((t + 1) & 1);
  }

  // ---- epilogue: l reduce (once), normalize, store ----
  {
    float lv = l_;
    lv += __shfl_xor(lv, 16);
    lv += __shfl_xor(lv, 32);   // lv = l_total[q=col] on every lane
#pragma unroll
    for (int r = 0; r < 4; ++r) {
      const float lt = __shfl(lv, 4 * hi + r);   // l for this lane's output row
      const float inv = 1.0f / lt;
      const int q = q0 + 4 * hi + r;
      float* op = out + ((size_t)b * SEQ + q) * (NH * DH) + h * DH;
#pragma unroll
      for (int nc = 0; nc < 4; ++nc)
        op[nc * 16 + col] = oacc[nc][r] * inv;
    }
  }
}

extern "C" void kernel_launch(void* const* d_in, const int* in_sizes, int n_in,
                              void* d_out, int out_size, void* d_ws, size_t ws_size,
                              hipStream_t stream) {
  const float* qkv = (const float*)d_in[0];
  float* out = (float*)d_out;
  (void)in_sizes; (void)n_in; (void)out_size; (void)d_ws; (void)ws_size;
  attn_fwd<<<dim3(1024), dim3(256), 0, stream>>>(qkv, out);
}